// Round 8
// baseline (643.699 us; speedup 1.0000x reference)
//
#include <hip/hip_runtime.h>

#define N_WORDS 262144
#define N_TAGS  512
#define BDIM    768
#define MDIM    128
#define KS      32              // K per slice
#define NSL     (BDIM / KS)     // 24 slices
#define BW      32              // words per block
#define EPAD    40              // sE row stride in ushorts (80B -> conflict-free)

typedef __attribute__((ext_vector_type(8))) short  bf16x8;
typedef __attribute__((ext_vector_type(4))) float  f32x4;

// RNE fp32 -> bf16 (inputs finite)
__device__ inline unsigned bf16_1(float a) {
    union { float f; unsigned u; } ua; ua.f = a;
    unsigned x = ua.u;
    x += 0x7fffu + ((x >> 16) & 1u);
    return x >> 16;
}
// pack two fp32 -> (bf16(b)<<16)|bf16(a)
__device__ inline unsigned bf16_2(float a, float b) {
    union { float f; unsigned u; } ua, ub; ua.f = a; ub.f = b;
    unsigned x = ua.u, y = ub.u;
    x += 0x7fffu + ((x >> 16) & 1u);
    y += 0x7fffu + ((y >> 16) & 1u);
    return (x >> 16) | (y & 0xffff0000u);
}

// ---------------------------------------------------------------------------
// tags: Tm[t][m] = tags_embed[t].tags_W[m] + tags_b[m]  (fp32)
//   Tbf[t][m] = bf16(2*Tm)                  (k-contiguous rows)
//   cvec[t]   = 2*words_b.Tm_t - ||Tm_t||^2 (fp32)
// ---------------------------------------------------------------------------
__global__ __launch_bounds__(128) void tags_kernel(
    const float* __restrict__ tags_embed, const float* __restrict__ tags_W,
    const float* __restrict__ tags_b, const float* __restrict__ words_b,
    unsigned short* __restrict__ Tbf, float* __restrict__ cvec)
{
    __shared__ __align__(16) float sE[BDIM];
    __shared__ float red[128];
    const int t = blockIdx.x;
    const int m = threadIdx.x;

    for (int i = m; i < BDIM; i += 128) sE[i] = tags_embed[(size_t)t * BDIM + i];
    __syncthreads();

    float acc = tags_b[m];
    const float* Wr = tags_W + (size_t)m * BDIM;
    #pragma unroll 8
    for (int b = 0; b < BDIM; b += 4) {
        float4 w4 = *reinterpret_cast<const float4*>(Wr + b);
        float4 e4 = *reinterpret_cast<const float4*>(&sE[b]);
        acc += w4.x * e4.x + w4.y * e4.y + w4.z * e4.z + w4.w * e4.w;
    }
    Tbf[(size_t)t * MDIM + m] = (unsigned short)bf16_1(2.0f * acc);

    red[m] = acc * (2.0f * words_b[m] - acc);
    __syncthreads();
    for (int s = 64; s > 0; s >>= 1) {
        if (m < s) red[m] += red[m + s];
        __syncthreads();
    }
    if (m == 0) cvec[t] = red[0];
}

// ---------------------------------------------------------------------------
// wt: Wtbf[768][128] bf16 = transpose(words_W fp32 [128][768])
// ---------------------------------------------------------------------------
__global__ __launch_bounds__(256) void wt_kernel(
    const float* __restrict__ W, unsigned short* __restrict__ Wtbf)
{
    __shared__ float sT[32][33];
    const int bm = blockIdx.x & 3, bk = blockIdx.x >> 2;
    const int m0 = bm * 32, k0 = bk * 32;
    const int r = threadIdx.x >> 3, c = threadIdx.x & 7;

    f32x4 w4 = *reinterpret_cast<const f32x4*>(W + (size_t)(m0 + r) * BDIM + k0 + c * 4);
    sT[r][c * 4 + 0] = w4.x;  sT[r][c * 4 + 1] = w4.y;
    sT[r][c * 4 + 2] = w4.z;  sT[r][c * 4 + 3] = w4.w;
    __syncthreads();

    unsigned lo = bf16_2(sT[c * 4 + 0][r], sT[c * 4 + 1][r]);
    unsigned hi = bf16_2(sT[c * 4 + 2][r], sT[c * 4 + 3][r]);
    unsigned long long p = ((unsigned long long)hi << 32) | lo;
    *reinterpret_cast<unsigned long long*>(Wtbf + (size_t)(k0 + r) * MDIM + m0 + c * 4) = p;
}

// ---------------------------------------------------------------------------
// gt: G[tag][k] = sum_m Wt[k][m] * (2T)[tag][m]  -> stored SLICE-MAJOR:
//     GtSl[s][tag][k%32], s = k/32.
// ---------------------------------------------------------------------------
__global__ __launch_bounds__(64) void gt_kernel(
    const unsigned short* __restrict__ Wtbf, const unsigned short* __restrict__ Tbf,
    unsigned short* __restrict__ GtSl)
{
    const int kt = blockIdx.x % 48, tg = blockIdx.x / 48;
    const int k0 = kt * 16, t0 = tg * 64;
    const int n = threadIdx.x & 15, q = threadIdx.x >> 4;

    bf16x8 a[4];
    #pragma unroll
    for (int ks = 0; ks < 4; ++ks)
        a[ks] = *reinterpret_cast<const bf16x8*>(
            Wtbf + (size_t)(k0 + n) * MDIM + ks * 32 + q * 8);

    const int s2  = kt >> 1;
    const int off = (kt & 1) * 16 + 4 * q;     // k offset within slice

    #pragma unroll
    for (int tt = 0; tt < 4; ++tt) {
        f32x4 acc = (f32x4){0.f, 0.f, 0.f, 0.f};
        #pragma unroll
        for (int ks = 0; ks < 4; ++ks) {
            bf16x8 b = *reinterpret_cast<const bf16x8*>(
                Tbf + (size_t)(t0 + tt * 16 + n) * MDIM + ks * 32 + q * 8);
            acc = __builtin_amdgcn_mfma_f32_16x16x32_bf16(a[ks], b, acc, 0, 0, 0);
        }
        unsigned lo = bf16_2(acc.x, acc.y);
        unsigned hi = bf16_2(acc.z, acc.w);
        unsigned long long p = ((unsigned long long)hi << 32) | lo;
        *reinterpret_cast<unsigned long long*>(
            GtSl + (size_t)s2 * (N_TAGS * KS) + (size_t)(t0 + tt * 16 + n) * KS + off) = p;
    }
}

// ---------------------------------------------------------------------------
// main: E-in-registers K-sliced GEMM + fused softmax.
// 8192 blocks x 512 thr (8 waves). Block = 32 words x 512 tags.
// Prologue: whole E panel (32x768) -> 24 packed-bf16 regs per thread.
// Per slice: half-threads ds_write E slice from regs (dbuf, padded rows);
//   A-frags (Gt) read per-lane straight from L2, prefetched 1 slice ahead;
//   8 MFMAs per wave; barrier = s_waitcnt lgkmcnt(0); s_barrier (global
//   loads stay in flight across it).
// ---------------------------------------------------------------------------
__global__ __launch_bounds__(512, 4) void main_kernel(
    const float* __restrict__ embed,                 // [N][768] fp32
    const unsigned short* __restrict__ GtSl,         // [24][512][32] bf16
    const float* __restrict__ cvec,                  // [512] fp32
    float* __restrict__ out_logp, float* __restrict__ out_p)
{
    __shared__ __align__(16) unsigned short sE[2][BW * EPAD];   // 5 KB
    __shared__ float sMx[8][BW];
    __shared__ float sSm[8][BW];

    const int tid  = threadIdx.x;
    const int lane = tid & 63;
    const int v    = tid >> 6;       // wave 0..7 -> tags v*64..+63
    const int n    = lane & 15;
    const int q    = lane >> 4;
    const int we   = tid >> 4;       // staging word 0..31
    const int kp   = tid & 15;       // staging k-part 0..15
    const int w0   = blockIdx.x * BW;

    // ---- prologue: E panel -> 24 packed bf16 pairs per thread ----
    // thread holds E[w0+we][kp*4 + r*64 .. +3] for r=0..11
    unsigned pk[24];
    {
        const float* eS = embed + (size_t)(w0 + we) * BDIM + kp * 4;
        f32x4 e[12];
        #pragma unroll
        for (int r = 0; r < 12; ++r)
            e[r] = *reinterpret_cast<const f32x4*>(eS + r * 64);
        #pragma unroll
        for (int r = 0; r < 12; ++r) {
            pk[2 * r]     = bf16_2(e[r].x, e[r].y);
            pk[2 * r + 1] = bf16_2(e[r].z, e[r].w);
        }
    }

    // slice 0 (even -> kp<8 holds its data at in-slice offset (kp&7)*4)
    if (kp < 8)
        *reinterpret_cast<unsigned long long*>(&sE[0][we * EPAD + (kp & 7) * 4]) =
            ((unsigned long long)pk[1] << 32) | pk[0];

    // A-frag base: GtSl[s][v*64 + mt*16 + n][q*8]
    const unsigned short* Ab = GtSl + (size_t)(v * 64 + n) * KS + q * 8;
    bf16x8 aC[4], aN[4];
    #pragma unroll
    for (int mt = 0; mt < 4; ++mt)
        aC[mt] = *reinterpret_cast<const bf16x8*>(Ab + mt * 512);

    asm volatile("s_waitcnt lgkmcnt(0)\n\ts_barrier" ::: "memory");

    f32x4 acc[4][2];
    #pragma unroll
    for (int mt = 0; mt < 4; ++mt) {
        acc[mt][0] = (f32x4){0.f, 0.f, 0.f, 0.f};
        acc[mt][1] = (f32x4){0.f, 0.f, 0.f, 0.f};
    }

    #pragma unroll
    for (int s = 0; s < NSL; ++s) {
        const int cur = s & 1;

        if (s + 1 < NSL) {
            // E ds_write slice s+1 from regs (static pack index)
            if ((kp >> 3) == ((s + 1) & 1)) {
                const int r = (s + 1) >> 1;
                *reinterpret_cast<unsigned long long*>(
                    &sE[cur ^ 1][we * EPAD + (kp & 7) * 4]) =
                    ((unsigned long long)pk[2 * r + 1] << 32) | pk[2 * r];
            }
            // A prefetch slice s+1 (stays in flight across the barrier)
            #pragma unroll
            for (int mt = 0; mt < 4; ++mt)
                aN[mt] = *reinterpret_cast<const bf16x8*>(
                    Ab + (size_t)(s + 1) * (N_TAGS * KS) + mt * 512);
        }

        // compute slice s
        bf16x8 b0 = *reinterpret_cast<const bf16x8*>(&sE[cur][n * EPAD + q * 8]);
        bf16x8 b1 = *reinterpret_cast<const bf16x8*>(&sE[cur][(16 + n) * EPAD + q * 8]);
        #pragma unroll
        for (int mt = 0; mt < 4; ++mt) {
            acc[mt][0] = __builtin_amdgcn_mfma_f32_16x16x32_bf16(aC[mt], b0, acc[mt][0], 0, 0, 0);
            acc[mt][1] = __builtin_amdgcn_mfma_f32_16x16x32_bf16(aC[mt], b1, acc[mt][1], 0, 0, 0);
        }

        if (s + 1 < NSL) {
            asm volatile("s_waitcnt lgkmcnt(0)\n\ts_barrier" ::: "memory");
            #pragma unroll
            for (int mt = 0; mt < 4; ++mt) aC[mt] = aN[mt];
        }
    }

    // ---- + cvec: tag = v*64 + mt*16 + 4q + r ----
    #pragma unroll
    for (int mt = 0; mt < 4; ++mt) {
        f32x4 c4 = *reinterpret_cast<const f32x4*>(cvec + v * 64 + mt * 16 + 4 * q);
        acc[mt][0] += c4;
        acc[mt][1] += c4;
    }

    // ---- per-word partial softmax (wave: 64 tags x 32 words) ----
    float mx[2], sm[2];
    #pragma unroll
    for (int wt = 0; wt < 2; ++wt) {
        float m = -3.0e38f;
        #pragma unroll
        for (int mt = 0; mt < 4; ++mt)
            m = fmaxf(m, fmaxf(fmaxf(acc[mt][wt].x, acc[mt][wt].y),
                               fmaxf(acc[mt][wt].z, acc[mt][wt].w)));
        m = fmaxf(m, __shfl_xor(m, 16, 64));
        m = fmaxf(m, __shfl_xor(m, 32, 64));
        mx[wt] = m;
        float s = 0.f;
        #pragma unroll
        for (int mt = 0; mt < 4; ++mt)
            s += __expf(acc[mt][wt].x - m) + __expf(acc[mt][wt].y - m)
               + __expf(acc[mt][wt].z - m) + __expf(acc[mt][wt].w - m);
        s += __shfl_xor(s, 16, 64);
        s += __shfl_xor(s, 32, 64);
        sm[wt] = s;
    }
    if (q == 0) {
        sMx[v][n]      = mx[0];
        sMx[v][16 + n] = mx[1];
        sSm[v][n]      = sm[0];
        sSm[v][16 + n] = sm[1];
    }
    __syncthreads();

    // ---- cross-wave combine + epilogue stores ----
    #pragma unroll
    for (int wt = 0; wt < 2; ++wt) {
        const int wd = wt * 16 + n;
        float M = sMx[0][wd];
        #pragma unroll
        for (int u = 1; u < 8; ++u) M = fmaxf(M, sMx[u][wd]);
        float S = 0.f;
        #pragma unroll
        for (int u = 0; u < 8; ++u) S += sSm[u][wd] * __expf(sMx[u][wd] - M);
        const float neg = M + __logf(S);

        const size_t row = (size_t)(w0 + wd) * N_TAGS + v * 64 + 4 * q;
        #pragma unroll
        for (int mt = 0; mt < 4; ++mt) {
            f32x4 lp, pp;
            lp.x = acc[mt][wt].x - neg;  pp.x = __expf(lp.x);
            lp.y = acc[mt][wt].y - neg;  pp.y = __expf(lp.y);
            lp.z = acc[mt][wt].z - neg;  pp.z = __expf(lp.z);
            lp.w = acc[mt][wt].w - neg;  pp.w = __expf(lp.w);
            *reinterpret_cast<f32x4*>(out_logp + row + mt * 16) = lp;
            *reinterpret_cast<f32x4*>(out_p    + row + mt * 16) = pp;
        }
    }
}

extern "C" void kernel_launch(void* const* d_in, const int* in_sizes, int n_in,
                              void* d_out, int out_size, void* d_ws, size_t ws_size,
                              hipStream_t stream) {
    const float* tags_embed  = (const float*)d_in[0];
    const float* words_embed = (const float*)d_in[1];
    const float* tags_W      = (const float*)d_in[2];
    const float* tags_b      = (const float*)d_in[3];
    const float* words_W     = (const float*)d_in[4];
    const float* words_b     = (const float*)d_in[5];

    float* out_logp = (float*)d_out;
    float* out_p    = out_logp + (size_t)N_WORDS * N_TAGS;

    // ws: Tbf [512][128] bf16 | cvec [512] f32 | Wtbf [768][128] bf16 |
    //     GtSl [24][512][32] bf16
    unsigned short* Tbf  = (unsigned short*)d_ws;
    float*          cvec = (float*)(Tbf + (size_t)N_TAGS * MDIM);
    unsigned short* Wtbf = (unsigned short*)(cvec + N_TAGS);
    unsigned short* GtSl = Wtbf + (size_t)BDIM * MDIM;

    tags_kernel<<<N_TAGS, 128, 0, stream>>>(tags_embed, tags_W, tags_b, words_b, Tbf, cvec);
    wt_kernel<<<96, 256, 0, stream>>>(words_W, Wtbf);
    gt_kernel<<<384, 64, 0, stream>>>(Wtbf, Tbf, GtSl);
    main_kernel<<<N_WORDS / BW, 512, 0, stream>>>(
        words_embed, GtSl, cvec, out_logp, out_p);
}

// Round 9
// 615.890 us; speedup vs baseline: 1.0452x; 1.0452x over previous
//
#include <hip/hip_runtime.h>

#define N_WORDS 262144
#define N_TAGS  512
#define BDIM    768
#define MDIM    128
#define KS      32              // K per slice
#define NSL     (BDIM / KS)     // 24 slices
#define BW      64              // words per block

typedef __attribute__((ext_vector_type(8))) short  bf16x8;
typedef __attribute__((ext_vector_type(4))) float  f32x4;

// RNE fp32 -> bf16 (inputs finite)
__device__ inline unsigned bf16_1(float a) {
    union { float f; unsigned u; } ua; ua.f = a;
    unsigned x = ua.u;
    x += 0x7fffu + ((x >> 16) & 1u);
    return x >> 16;
}
// pack two fp32 -> (bf16(b)<<16)|bf16(a)
__device__ inline unsigned bf16_2(float a, float b) {
    union { float f; unsigned u; } ua, ub; ua.f = a; ub.f = b;
    unsigned x = ua.u, y = ub.u;
    x += 0x7fffu + ((x >> 16) & 1u);
    y += 0x7fffu + ((y >> 16) & 1u);
    return (x >> 16) | (y & 0xffff0000u);
}

// ---------------------------------------------------------------------------
// tags: Tm[t][m] = tags_embed[t].tags_W[m] + tags_b[m]  (fp32)
//   Tbf[t][m] = bf16(2*Tm)                  (k-contiguous rows)
//   cvec[t]   = 2*words_b.Tm_t - ||Tm_t||^2 (fp32)
// ---------------------------------------------------------------------------
__global__ __launch_bounds__(128) void tags_kernel(
    const float* __restrict__ tags_embed, const float* __restrict__ tags_W,
    const float* __restrict__ tags_b, const float* __restrict__ words_b,
    unsigned short* __restrict__ Tbf, float* __restrict__ cvec)
{
    __shared__ __align__(16) float sE[BDIM];
    __shared__ float red[128];
    const int t = blockIdx.x;
    const int m = threadIdx.x;

    for (int i = m; i < BDIM; i += 128) sE[i] = tags_embed[(size_t)t * BDIM + i];
    __syncthreads();

    float acc = tags_b[m];
    const float* Wr = tags_W + (size_t)m * BDIM;
    #pragma unroll 8
    for (int b = 0; b < BDIM; b += 4) {
        float4 w4 = *reinterpret_cast<const float4*>(Wr + b);
        float4 e4 = *reinterpret_cast<const float4*>(&sE[b]);
        acc += w4.x * e4.x + w4.y * e4.y + w4.z * e4.z + w4.w * e4.w;
    }
    Tbf[(size_t)t * MDIM + m] = (unsigned short)bf16_1(2.0f * acc);

    red[m] = acc * (2.0f * words_b[m] - acc);
    __syncthreads();
    for (int s = 64; s > 0; s >>= 1) {
        if (m < s) red[m] += red[m + s];
        __syncthreads();
    }
    if (m == 0) cvec[t] = red[0];
}

// ---------------------------------------------------------------------------
// wt: Wtbf[768][128] bf16 = transpose(words_W fp32 [128][768])
// ---------------------------------------------------------------------------
__global__ __launch_bounds__(256) void wt_kernel(
    const float* __restrict__ W, unsigned short* __restrict__ Wtbf)
{
    __shared__ float sT[32][33];
    const int bm = blockIdx.x & 3, bk = blockIdx.x >> 2;
    const int m0 = bm * 32, k0 = bk * 32;
    const int r = threadIdx.x >> 3, c = threadIdx.x & 7;

    f32x4 w4 = *reinterpret_cast<const f32x4*>(W + (size_t)(m0 + r) * BDIM + k0 + c * 4);
    sT[r][c * 4 + 0] = w4.x;  sT[r][c * 4 + 1] = w4.y;
    sT[r][c * 4 + 2] = w4.z;  sT[r][c * 4 + 3] = w4.w;
    __syncthreads();

    unsigned lo = bf16_2(sT[c * 4 + 0][r], sT[c * 4 + 1][r]);
    unsigned hi = bf16_2(sT[c * 4 + 2][r], sT[c * 4 + 3][r]);
    unsigned long long p = ((unsigned long long)hi << 32) | lo;
    *reinterpret_cast<unsigned long long*>(Wtbf + (size_t)(k0 + r) * MDIM + m0 + c * 4) = p;
}

// ---------------------------------------------------------------------------
// gt: G[tag][k] = sum_m Wt[k][m] * (2T)[tag][m]  -> stored SLICE-MAJOR:
//     GtSl[s][tag][k%32], s = k/32.
// ---------------------------------------------------------------------------
__global__ __launch_bounds__(64) void gt_kernel(
    const unsigned short* __restrict__ Wtbf, const unsigned short* __restrict__ Tbf,
    unsigned short* __restrict__ GtSl)
{
    const int kt = blockIdx.x % 48, tg = blockIdx.x / 48;
    const int k0 = kt * 16, t0 = tg * 64;
    const int n = threadIdx.x & 15, q = threadIdx.x >> 4;

    bf16x8 a[4];
    #pragma unroll
    for (int ks = 0; ks < 4; ++ks)
        a[ks] = *reinterpret_cast<const bf16x8*>(
            Wtbf + (size_t)(k0 + n) * MDIM + ks * 32 + q * 8);

    const int s2  = kt >> 1;
    const int off = (kt & 1) * 16 + 4 * q;     // k offset within slice

    #pragma unroll
    for (int tt = 0; tt < 4; ++tt) {
        f32x4 acc = (f32x4){0.f, 0.f, 0.f, 0.f};
        #pragma unroll
        for (int ks = 0; ks < 4; ++ks) {
            bf16x8 b = *reinterpret_cast<const bf16x8*>(
                Tbf + (size_t)(t0 + tt * 16 + n) * MDIM + ks * 32 + q * 8);
            acc = __builtin_amdgcn_mfma_f32_16x16x32_bf16(a[ks], b, acc, 0, 0, 0);
        }
        unsigned lo = bf16_2(acc.x, acc.y);
        unsigned hi = bf16_2(acc.z, acc.w);
        unsigned long long p = ((unsigned long long)hi << 32) | lo;
        *reinterpret_cast<unsigned long long*>(
            GtSl + (size_t)s2 * (N_TAGS * KS) + (size_t)(t0 + tt * 16 + n) * KS + off) = p;
    }
}

// ---------------------------------------------------------------------------
// main: K-sliced GEMM + fused softmax. 4096 blocks x 512 thr (8 waves).
// Block = 64 words x 512 tags; wave v = tags v*64..+63 x all 64 words.
// A-frags (Gt): per-wave register loads from L2, prefetched 1 slice ahead.
// E: depth-2 reg pipeline (load s -> ds_write s+2 -> ds_read s+3),
//    XOR-swizzled LDS rows (byte ^ ((row&3)<<4)).
// Barrier: lgkmcnt(0) only -- ALL global loads fly across it; the compiler
// emits exact counted vmcnt per consumer.
// ---------------------------------------------------------------------------
__global__ __launch_bounds__(512, 4) void main_kernel(
    const float* __restrict__ embed,                 // [N][768] fp32
    const unsigned short* __restrict__ GtSl,         // [24][512][32] bf16
    const float* __restrict__ cvec,                  // [512] fp32
    float* __restrict__ out_logp, float* __restrict__ out_p)
{
    __shared__ __align__(16) unsigned short sE[2][BW * KS];   // 2 x 4 KB
    __shared__ float sMx[8][BW];
    __shared__ float sSm[8][BW];

    const int tid  = threadIdx.x;
    const int lane = tid & 63;
    const int v    = tid >> 6;       // wave 0..7 -> tags v*64..+63
    const int n    = lane & 15;
    const int q    = lane >> 4;
    const int we   = tid >> 3;       // staging word 0..63
    const int kp   = tid & 7;        // staging 8B-granule 0..7
    const int w0   = blockIdx.x * BW;

    const float* eSrc = embed + (size_t)(w0 + we) * BDIM + kp * 4;
    // swizzled ushort index for the staging ds_write (8B granule)
    const int wrOff = we * KS + (((kp * 8) ^ ((we & 3) << 4)) >> 1);

    const unsigned short* Ab = GtSl + (size_t)(v * 64 + n) * KS + q * 8;

    // ---- prologue ----
    f32x4 e0 = *reinterpret_cast<const f32x4*>(eSrc);            // E(0)
    bf16x8 aC[4], aN[4];
    #pragma unroll
    for (int mt = 0; mt < 4; ++mt)
        aC[mt] = *reinterpret_cast<const bf16x8*>(Ab + mt * (16 * KS));
    f32x4 eA = *reinterpret_cast<const f32x4*>(eSrc + KS);       // E(1)
    f32x4 eB = *reinterpret_cast<const f32x4*>(eSrc + 2 * KS);   // E(2)
    {
        unsigned lo = bf16_2(e0.x, e0.y), hi = bf16_2(e0.z, e0.w);
        *reinterpret_cast<unsigned long long*>(&sE[0][wrOff]) =
            ((unsigned long long)hi << 32) | lo;
    }
    asm volatile("s_waitcnt lgkmcnt(0)\n\ts_barrier" ::: "memory");

    f32x4 acc[4][4];
    #pragma unroll
    for (int mt = 0; mt < 4; ++mt)
        #pragma unroll
        for (int wt = 0; wt < 4; ++wt)
            acc[mt][wt] = (f32x4){0.f, 0.f, 0.f, 0.f};

    #pragma unroll
    for (int s = 0; s < NSL; ++s) {
        const int cur = s & 1;

        // issue E-load for slice s+3 (written to LDS at s+2)
        f32x4 eN;
        if (s + 3 < NSL)
            eN = *reinterpret_cast<const f32x4*>(eSrc + (s + 3) * KS);

        if (s + 1 < NSL) {
            // A-frag prefetch slice s+1 (register, in flight across barrier)
            #pragma unroll
            for (int mt = 0; mt < 4; ++mt)
                aN[mt] = *reinterpret_cast<const bf16x8*>(
                    Ab + (size_t)(s + 1) * (N_TAGS * KS) + mt * (16 * KS));
            // ds_write E(s+1) from eA (loaded 2 slices ago)
            unsigned lo = bf16_2(eA.x, eA.y), hi = bf16_2(eA.z, eA.w);
            *reinterpret_cast<unsigned long long*>(&sE[cur ^ 1][wrOff]) =
                ((unsigned long long)hi << 32) | lo;
        }

        // compute slice s (swizzled B-frag reads)
        bf16x8 b[4];
        #pragma unroll
        for (int wt = 0; wt < 4; ++wt) {
            const int R = wt * 16 + n;
            b[wt] = *reinterpret_cast<const bf16x8*>(
                &sE[cur][R * KS + (((q * 16) ^ ((R & 3) << 4)) >> 1)]);
        }
        #pragma unroll
        for (int mt = 0; mt < 4; ++mt)
            #pragma unroll
            for (int wt = 0; wt < 4; ++wt)
                acc[mt][wt] = __builtin_amdgcn_mfma_f32_16x16x32_bf16(
                    aC[mt], b[wt], acc[mt][wt], 0, 0, 0);

        if (s + 1 < NSL) {
            asm volatile("s_waitcnt lgkmcnt(0)\n\ts_barrier" ::: "memory");
            eA = eB;
            #pragma unroll
            for (int mt = 0; mt < 4; ++mt) aC[mt] = aN[mt];
        }
        if (s + 3 < NSL) eB = eN;
    }

    // ---- + cvec: tag = v*64 + mt*16 + 4q + r ----
    #pragma unroll
    for (int mt = 0; mt < 4; ++mt) {
        f32x4 c4 = *reinterpret_cast<const f32x4*>(cvec + v * 64 + mt * 16 + 4 * q);
        #pragma unroll
        for (int wt = 0; wt < 4; ++wt) acc[mt][wt] += c4;
    }

    // ---- per-word partial softmax (wave: 64 tags x 64 words) ----
    float mx[4], sm[4];
    #pragma unroll
    for (int wt = 0; wt < 4; ++wt) {
        float m = -3.0e38f;
        #pragma unroll
        for (int mt = 0; mt < 4; ++mt)
            m = fmaxf(m, fmaxf(fmaxf(acc[mt][wt].x, acc[mt][wt].y),
                               fmaxf(acc[mt][wt].z, acc[mt][wt].w)));
        m = fmaxf(m, __shfl_xor(m, 16, 64));
        m = fmaxf(m, __shfl_xor(m, 32, 64));
        mx[wt] = m;
        float s = 0.f;
        #pragma unroll
        for (int mt = 0; mt < 4; ++mt)
            s += __expf(acc[mt][wt].x - m) + __expf(acc[mt][wt].y - m)
               + __expf(acc[mt][wt].z - m) + __expf(acc[mt][wt].w - m);
        s += __shfl_xor(s, 16, 64);
        s += __shfl_xor(s, 32, 64);
        sm[wt] = s;
    }
    if (q == 0) {
        #pragma unroll
        for (int wt = 0; wt < 4; ++wt) {
            sMx[v][wt * 16 + n] = mx[wt];
            sSm[v][wt * 16 + n] = sm[wt];
        }
    }
    __syncthreads();

    // ---- cross-wave combine + epilogue stores ----
    #pragma unroll
    for (int wt = 0; wt < 4; ++wt) {
        const int wd = wt * 16 + n;
        float M = sMx[0][wd];
        #pragma unroll
        for (int u = 1; u < 8; ++u) M = fmaxf(M, sMx[u][wd]);
        float S = 0.f;
        #pragma unroll
        for (int u = 0; u < 8; ++u) S += sSm[u][wd] * __expf(sMx[u][wd] - M);
        const float neg = M + __logf(S);

        const size_t row = (size_t)(w0 + wd) * N_TAGS + v * 64 + 4 * q;
        #pragma unroll
        for (int mt = 0; mt < 4; ++mt) {
            f32x4 lp, pp;
            lp.x = acc[mt][wt].x - neg;  pp.x = __expf(lp.x);
            lp.y = acc[mt][wt].y - neg;  pp.y = __expf(lp.y);
            lp.z = acc[mt][wt].z - neg;  pp.z = __expf(lp.z);
            lp.w = acc[mt][wt].w - neg;  pp.w = __expf(lp.w);
            *reinterpret_cast<f32x4*>(out_logp + row + mt * 16) = lp;
            *reinterpret_cast<f32x4*>(out_p    + row + mt * 16) = pp;
        }
    }
}

extern "C" void kernel_launch(void* const* d_in, const int* in_sizes, int n_in,
                              void* d_out, int out_size, void* d_ws, size_t ws_size,
                              hipStream_t stream) {
    const float* tags_embed  = (const float*)d_in[0];
    const float* words_embed = (const float*)d_in[1];
    const float* tags_W      = (const float*)d_in[2];
    const float* tags_b      = (const float*)d_in[3];
    const float* words_W     = (const float*)d_in[4];
    const float* words_b     = (const float*)d_in[5];

    float* out_logp = (float*)d_out;
    float* out_p    = out_logp + (size_t)N_WORDS * N_TAGS;

    // ws: Tbf [512][128] bf16 | cvec [512] f32 | Wtbf [768][128] bf16 |
    //     GtSl [24][512][32] bf16
    unsigned short* Tbf  = (unsigned short*)d_ws;
    float*          cvec = (float*)(Tbf + (size_t)N_TAGS * MDIM);
    unsigned short* Wtbf = (unsigned short*)(cvec + N_TAGS);
    unsigned short* GtSl = Wtbf + (size_t)BDIM * MDIM;

    tags_kernel<<<N_TAGS, 128, 0, stream>>>(tags_embed, tags_W, tags_b, words_b, Tbf, cvec);
    wt_kernel<<<96, 256, 0, stream>>>(words_W, Wtbf);
    gt_kernel<<<384, 64, 0, stream>>>(Wtbf, Tbf, GtSl);
    main_kernel<<<N_WORDS / BW, 512, 0, stream>>>(
        words_embed, GtSl, cvec, out_logp, out_p);
}